// Round 1
// baseline (2364.606 us; speedup 1.0000x reference)
//
#include <hip/hip_runtime.h>

#define NVOX   98280
#define S_SETS 2730
#define L_SET  36
#define D_MODEL 192
#define D_FF    384
#define N_HEADS 8
#define H_DIM   24

// ---------------------------------------------------------------------------
// Tiled f32 GEMM: C[n, colBase+c] = act(sum_k A[n,k] * W[colBase+c, k] + b[c])
// A: (n, K) row-major, W: (O, K) row-major. BM=128, BN=64, BK=64.
// 256 threads, each computes 8x4 outputs.
// ---------------------------------------------------------------------------
template<int K, bool RELU>
__global__ __launch_bounds__(256)
void gemm_kernel(const float* __restrict__ A, const float* __restrict__ W,
                 const float* __restrict__ bias, float* __restrict__ C,
                 int n, int ldc)
{
    __shared__ float As[64][132];   // [k][m], pad 132 keeps float4 align + spreads banks
    __shared__ float Ws[64][68];    // [k][c]
    const int rowBase = blockIdx.x * 128;
    const int colBase = blockIdx.y * 64;
    const int tid = threadIdx.x;
    const int kq = tid & 15;        // which k-quad this thread loads
    const int rr = tid >> 4;        // 0..15
    const int tx = tid & 15;        // output col group
    const int ty = tid >> 4;        // output row group

    float acc[8][4];
    #pragma unroll
    for (int i = 0; i < 8; ++i)
        #pragma unroll
        for (int j = 0; j < 4; ++j) acc[i][j] = 0.f;

    for (int k0 = 0; k0 < K; k0 += 64) {
        const int kk = k0 + kq * 4;
        #pragma unroll
        for (int i = 0; i < 8; ++i) {           // A tile: 128 rows x 64 k
            int r = rr + 16 * i;
            int grow = rowBase + r;
            float4 a = make_float4(0.f, 0.f, 0.f, 0.f);
            if (grow < n) a = *(const float4*)(A + (size_t)grow * K + kk);
            As[kq*4+0][r] = a.x; As[kq*4+1][r] = a.y;
            As[kq*4+2][r] = a.z; As[kq*4+3][r] = a.w;
        }
        #pragma unroll
        for (int i = 0; i < 4; ++i) {           // W tile: 64 cols x 64 k
            int c = rr + 16 * i;
            float4 w = *(const float4*)(W + (size_t)(colBase + c) * K + kk);
            Ws[kq*4+0][c] = w.x; Ws[kq*4+1][c] = w.y;
            Ws[kq*4+2][c] = w.z; Ws[kq*4+3][c] = w.w;
        }
        __syncthreads();
        #pragma unroll 16
        for (int k = 0; k < 64; ++k) {
            float4 a0 = *(const float4*)&As[k][ty*8];
            float4 a1 = *(const float4*)&As[k][ty*8+4];
            float4 w  = *(const float4*)&Ws[k][tx*4];
            float av[8] = {a0.x,a0.y,a0.z,a0.w,a1.x,a1.y,a1.z,a1.w};
            float wv[4] = {w.x,w.y,w.z,w.w};
            #pragma unroll
            for (int i = 0; i < 8; ++i)
                #pragma unroll
                for (int j = 0; j < 4; ++j)
                    acc[i][j] = fmaf(av[i], wv[j], acc[i][j]);
        }
        __syncthreads();
    }
    const float4 bv = *(const float4*)(bias + colBase + tx*4);
    #pragma unroll
    for (int i = 0; i < 8; ++i) {
        int grow = rowBase + ty*8 + i;
        if (grow < n) {
            float4 o;
            o.x = acc[i][0] + bv.x; o.y = acc[i][1] + bv.y;
            o.z = acc[i][2] + bv.z; o.w = acc[i][3] + bv.w;
            if (RELU) {
                o.x = fmaxf(o.x, 0.f); o.y = fmaxf(o.y, 0.f);
                o.z = fmaxf(o.z, 0.f); o.w = fmaxf(o.w, 0.f);
            }
            *(float4*)(C + (size_t)grow * ldc + colBase + tx*4) = o;
        }
    }
}

// ---------------------------------------------------------------------------
// QKV GEMM with fused gather: rows are set-order f, A-row = x[inds[f]] (+pos for Q,K).
// K=192, output (N, 576): cols 0..383 from qk=x+pos, cols 384..575 from sf=x.
// ---------------------------------------------------------------------------
__global__ __launch_bounds__(256)
void qkv_gemm_kernel(const float* __restrict__ x, const float* __restrict__ pos,
                     const int* __restrict__ inds,
                     const float* __restrict__ W, const float* __restrict__ bias,
                     float* __restrict__ C, int n)
{
    const int K = D_MODEL;
    __shared__ float As[64][132];
    __shared__ float Ws[64][68];
    const int rowBase = blockIdx.x * 128;
    const int colBase = blockIdx.y * 64;
    const bool qkmode = (colBase < 384);
    const int tid = threadIdx.x;
    const int kq = tid & 15;
    const int rr = tid >> 4;
    const int tx = tid & 15;
    const int ty = tid >> 4;

    float acc[8][4];
    #pragma unroll
    for (int i = 0; i < 8; ++i)
        #pragma unroll
        for (int j = 0; j < 4; ++j) acc[i][j] = 0.f;

    for (int k0 = 0; k0 < K; k0 += 64) {
        const int kk = k0 + kq * 4;
        #pragma unroll
        for (int i = 0; i < 8; ++i) {
            int r = rr + 16 * i;
            int grow = rowBase + r;
            float4 a = make_float4(0.f, 0.f, 0.f, 0.f);
            if (grow < n) {
                int v = inds[grow];
                a = *(const float4*)(x + (size_t)v * K + kk);
                if (qkmode) {
                    float4 p = *(const float4*)(pos + (size_t)v * K + kk);
                    a.x += p.x; a.y += p.y; a.z += p.z; a.w += p.w;
                }
            }
            As[kq*4+0][r] = a.x; As[kq*4+1][r] = a.y;
            As[kq*4+2][r] = a.z; As[kq*4+3][r] = a.w;
        }
        #pragma unroll
        for (int i = 0; i < 4; ++i) {
            int c = rr + 16 * i;
            float4 w = *(const float4*)(W + (size_t)(colBase + c) * K + kk);
            Ws[kq*4+0][c] = w.x; Ws[kq*4+1][c] = w.y;
            Ws[kq*4+2][c] = w.z; Ws[kq*4+3][c] = w.w;
        }
        __syncthreads();
        #pragma unroll 16
        for (int k = 0; k < 64; ++k) {
            float4 a0 = *(const float4*)&As[k][ty*8];
            float4 a1 = *(const float4*)&As[k][ty*8+4];
            float4 w  = *(const float4*)&Ws[k][tx*4];
            float av[8] = {a0.x,a0.y,a0.z,a0.w,a1.x,a1.y,a1.z,a1.w};
            float wv[4] = {w.x,w.y,w.z,w.w};
            #pragma unroll
            for (int i = 0; i < 8; ++i)
                #pragma unroll
                for (int j = 0; j < 4; ++j)
                    acc[i][j] = fmaf(av[i], wv[j], acc[i][j]);
        }
        __syncthreads();
    }
    const float4 bv = *(const float4*)(bias + colBase + tx*4);
    #pragma unroll
    for (int i = 0; i < 8; ++i) {
        int grow = rowBase + ty*8 + i;
        if (grow < n) {
            float4 o;
            o.x = acc[i][0] + bv.x; o.y = acc[i][1] + bv.y;
            o.z = acc[i][2] + bv.z; o.w = acc[i][3] + bv.w;
            *(float4*)(C + (size_t)grow * 576 + colBase + tx*4) = o;
        }
    }
}

// ---------------------------------------------------------------------------
// Attention: one wave per (set, head). K,V staged in LDS; lanes 0..35 own q-rows.
// qkv layout: row f=(s*36+l), [0:192)=Q, [192:384)=K, [384:576)=V, head h at h*24.
// ---------------------------------------------------------------------------
__global__ __launch_bounds__(64)
void attn_kernel(const float* __restrict__ qkv, const unsigned char* __restrict__ mask,
                 float* __restrict__ attn_out)
{
    const int sb = blockIdx.x;
    const int s = sb >> 3;
    const int h = sb & 7;
    __shared__ float Ks[L_SET][H_DIM];
    __shared__ float Vs[L_SET][H_DIM];
    const int lane = threadIdx.x;

    for (int t = lane; t < L_SET * 6; t += 64) {   // 216 float4s per matrix
        int l = t / 6;
        int j = t - l * 6;
        size_t base = ((size_t)(s * L_SET + l)) * 576 + 192 + h * H_DIM + j * 4;
        *(float4*)&Ks[l][j*4] = *(const float4*)(qkv + base);
        *(float4*)&Vs[l][j*4] = *(const float4*)(qkv + base + 192);
    }
    __syncthreads();

    if (lane < L_SET) {
        float q[H_DIM];
        size_t qb = ((size_t)(s * L_SET + lane)) * 576 + h * H_DIM;
        #pragma unroll
        for (int j = 0; j < 6; ++j) {
            float4 t4 = *(const float4*)(qkv + qb + j*4);
            q[j*4+0] = t4.x; q[j*4+1] = t4.y; q[j*4+2] = t4.z; q[j*4+3] = t4.w;
        }
        float sc[L_SET];
        float mx = -1e30f;
        #pragma unroll
        for (int m = 0; m < L_SET; ++m) {
            float a = 0.f;
            #pragma unroll
            for (int d = 0; d < H_DIM; ++d) a = fmaf(q[d], Ks[m][d], a);
            a *= 0.20412414523193154f;             // 1/sqrt(24)
            if (mask[(size_t)s * L_SET + m] != 0) a = -1e9f;
            sc[m] = a;
            mx = fmaxf(mx, a);
        }
        float ssum = 0.f;
        #pragma unroll
        for (int m = 0; m < L_SET; ++m) { float e = __expf(sc[m] - mx); sc[m] = e; ssum += e; }
        const float rinv = 1.f / ssum;
        float o[H_DIM];
        #pragma unroll
        for (int d = 0; d < H_DIM; ++d) o[d] = 0.f;
        #pragma unroll
        for (int m = 0; m < L_SET; ++m) {
            float p = sc[m] * rinv;
            #pragma unroll
            for (int d = 0; d < H_DIM; ++d) o[d] = fmaf(p, Vs[m][d], o[d]);
        }
        size_t ob = ((size_t)(s * L_SET + lane)) * D_MODEL + h * H_DIM;
        #pragma unroll
        for (int j = 0; j < 6; ++j) {
            float4 t4;
            t4.x = o[j*4+0]; t4.y = o[j*4+1]; t4.z = o[j*4+2]; t4.w = o[j*4+3];
            *(float4*)(attn_out + ob + j*4) = t4;
        }
    }
}

// ---------------------------------------------------------------------------
// Wave-wide sum (64 lanes)
// ---------------------------------------------------------------------------
__device__ __forceinline__ float wave_sum64(float v) {
    #pragma unroll
    for (int off = 32; off > 0; off >>= 1) v += __shfl_xor(v, off, 64);
    return v;
}

// LN1: x1[v] = LN(xin[v] + proj[f]) with v = inds[f]  (scatter + residual + LN)
__global__ __launch_bounds__(256)
void ln_scatter_kernel(const float* __restrict__ xin, const float* __restrict__ proj,
                       const int* __restrict__ inds,
                       const float* __restrict__ g, const float* __restrict__ be,
                       float* __restrict__ xout, int n)
{
    int f = blockIdx.x * 4 + (threadIdx.x >> 6);
    int lane = threadIdx.x & 63;
    if (f >= n) return;
    int v = inds[f];
    float4 t = make_float4(0.f, 0.f, 0.f, 0.f);
    if (lane < 48) {
        float4 a = *(const float4*)(xin + (size_t)v * D_MODEL + lane * 4);
        float4 p = *(const float4*)(proj + (size_t)f * D_MODEL + lane * 4);
        t.x = a.x + p.x; t.y = a.y + p.y; t.z = a.z + p.z; t.w = a.w + p.w;
    }
    float mean = wave_sum64(t.x + t.y + t.z + t.w) * (1.f / 192.f);
    float ss   = wave_sum64(t.x*t.x + t.y*t.y + t.z*t.z + t.w*t.w) * (1.f / 192.f);
    float inv = rsqrtf(ss - mean * mean + 1e-5f);
    if (lane < 48) {
        float4 gv = *(const float4*)(g + lane * 4);
        float4 bv = *(const float4*)(be + lane * 4);
        float4 o;
        o.x = (t.x - mean) * inv * gv.x + bv.x;
        o.y = (t.y - mean) * inv * gv.y + bv.y;
        o.z = (t.z - mean) * inv * gv.z + bv.z;
        o.w = (t.w - mean) * inv * gv.w + bv.w;
        *(float4*)(xout + (size_t)v * D_MODEL + lane * 4) = o;
    }
}

// LN2+LN3 fused: x2 = LN(x1[v]+f2[v]; g2,be2); out[v] = LN(x2 + xin[v]; gn,bn)
__global__ __launch_bounds__(256)
void ln_double_kernel(const float* __restrict__ x1, const float* __restrict__ f2,
                      const float* __restrict__ xin,
                      const float* __restrict__ g2, const float* __restrict__ be2,
                      const float* __restrict__ gn, const float* __restrict__ bn,
                      float* __restrict__ outp, int n)
{
    int v = blockIdx.x * 4 + (threadIdx.x >> 6);
    int lane = threadIdx.x & 63;
    if (v >= n) return;
    float4 t   = make_float4(0.f, 0.f, 0.f, 0.f);
    float4 idv = make_float4(0.f, 0.f, 0.f, 0.f);
    float4 g2v = t, b2v = t, gnv = t, bnv = t;
    if (lane < 48) {
        float4 a = *(const float4*)(x1 + (size_t)v * D_MODEL + lane * 4);
        float4 b = *(const float4*)(f2 + (size_t)v * D_MODEL + lane * 4);
        idv = *(const float4*)(xin + (size_t)v * D_MODEL + lane * 4);
        t.x = a.x + b.x; t.y = a.y + b.y; t.z = a.z + b.z; t.w = a.w + b.w;
        g2v = *(const float4*)(g2 + lane * 4);
        b2v = *(const float4*)(be2 + lane * 4);
        gnv = *(const float4*)(gn + lane * 4);
        bnv = *(const float4*)(bn + lane * 4);
    }
    float m1 = wave_sum64(t.x + t.y + t.z + t.w) * (1.f / 192.f);
    float s1 = wave_sum64(t.x*t.x + t.y*t.y + t.z*t.z + t.w*t.w) * (1.f / 192.f);
    float i1 = rsqrtf(s1 - m1 * m1 + 1e-5f);
    float4 t2 = make_float4(0.f, 0.f, 0.f, 0.f);
    if (lane < 48) {
        t2.x = (t.x - m1) * i1 * g2v.x + b2v.x + idv.x;
        t2.y = (t.y - m1) * i1 * g2v.y + b2v.y + idv.y;
        t2.z = (t.z - m1) * i1 * g2v.z + b2v.z + idv.z;
        t2.w = (t.w - m1) * i1 * g2v.w + b2v.w + idv.w;
    }
    float m2 = wave_sum64(t2.x + t2.y + t2.z + t2.w) * (1.f / 192.f);
    float s2 = wave_sum64(t2.x*t2.x + t2.y*t2.y + t2.z*t2.z + t2.w*t2.w) * (1.f / 192.f);
    float i2 = rsqrtf(s2 - m2 * m2 + 1e-5f);
    if (lane < 48) {
        float4 o;
        o.x = (t2.x - m2) * i2 * gnv.x + bnv.x;
        o.y = (t2.y - m2) * i2 * gnv.y + bnv.y;
        o.z = (t2.z - m2) * i2 * gnv.z + bnv.z;
        o.w = (t2.w - m2) * i2 * gnv.w + bnv.w;
        *(float4*)(outp + (size_t)v * D_MODEL + lane * 4) = o;
    }
}

// ---------------------------------------------------------------------------
extern "C" void kernel_launch(void* const* d_in, const int* in_sizes, int n_in,
                              void* d_out, int out_size, void* d_ws, size_t ws_size,
                              hipStream_t stream)
{
    (void)in_sizes; (void)n_in; (void)out_size;
    const int N = NVOX;
    const float* src = (const float*)d_in[0];
    const int* inds[2] = {(const int*)d_in[1], (const int*)d_in[2]};
    const unsigned char* mask[2] = {(const unsigned char*)d_in[3], (const unsigned char*)d_in[4]};
    const float* pos[2] = {(const float*)d_in[5], (const float*)d_in[6]};
    const float* Wqkv = (const float*)d_in[7];
    const float* bqkv = (const float*)d_in[8];
    const float* Wo   = (const float*)d_in[9];
    const float* bo   = (const float*)d_in[10];
    const float* W1   = (const float*)d_in[11];
    const float* b1   = (const float*)d_in[12];
    const float* W2   = (const float*)d_in[13];
    const float* b2   = (const float*)d_in[14];
    const float* g1   = (const float*)d_in[15];
    const float* be1  = (const float*)d_in[16];
    const float* g2   = (const float*)d_in[17];
    const float* be2  = (const float*)d_in[18];
    const float* gn   = (const float*)d_in[19];
    const float* bn   = (const float*)d_in[20];

    float* out = (float*)d_out;
    float* ws  = (float*)d_ws;

    if (ws_size < (size_t)N * 768 * sizeof(float)) return;  // need ~302 MB scratch

    // ws aliasing plan (lifetimes don't overlap):
    //   [0, 576N)     qkv  -> proj -> hbuf(384N) ; f2 at [384N, 576N)
    //   [576N, 768N)  attn_out -> x1
    float* qkvb  = ws;
    float* attnb = ws + (size_t)N * 576;
    float* projb = ws;
    float* x1b   = attnb;
    float* hb    = ws;
    float* f2b   = ws + (size_t)N * 384;

    const dim3 blk(256);
    for (int i = 0; i < 2; ++i) {
        const float* xin = (i == 0) ? src : out;
        qkv_gemm_kernel<<<dim3(768, 9), blk, 0, stream>>>(
            xin, pos[i], inds[i], Wqkv + (size_t)i * 576 * 192, bqkv + i * 576, qkvb, N);
        attn_kernel<<<dim3(S_SETS * N_HEADS), dim3(64), 0, stream>>>(qkvb, mask[i], attnb);
        gemm_kernel<192, false><<<dim3(768, 3), blk, 0, stream>>>(
            attnb, Wo + (size_t)i * 192 * 192, bo + i * 192, projb, N, 192);
        ln_scatter_kernel<<<dim3(24570), blk, 0, stream>>>(
            xin, projb, inds[i], g1 + i * 192, be1 + i * 192, x1b, N);
        gemm_kernel<192, true><<<dim3(768, 6), blk, 0, stream>>>(
            x1b, W1 + (size_t)i * 384 * 192, b1 + i * 384, hb, N, 384);
        gemm_kernel<384, false><<<dim3(768, 3), blk, 0, stream>>>(
            hb, W2 + (size_t)i * 192 * 384, b2 + i * 192, f2b, N, 192);
        ln_double_kernel<<<dim3(24570), blk, 0, stream>>>(
            x1b, f2b, xin, g2 + i * 192, be2 + i * 192, gn + i * 192, bn + i * 192, out, N);
    }
}

// Round 2
// 1155.069 us; speedup vs baseline: 2.0472x; 2.0472x over previous
//
#include <hip/hip_runtime.h>
#include <stdint.h>

#define NVOX   98280
#define S_SETS 2730
#define L_SET  36
#define D_MODEL 192
#define D_FF    384
#define N_HEADS 8
#define H_DIM   24

using s16x8 = __attribute__((ext_vector_type(8))) short;
using s16x4 = __attribute__((ext_vector_type(4))) short;
using f32x4 = __attribute__((ext_vector_type(4))) float;

__device__ __forceinline__ float bf2f(unsigned short h) {
    unsigned u = ((unsigned)h) << 16;
    return __builtin_bit_cast(float, u);
}
__device__ __forceinline__ unsigned short f2bf(float f) {
    unsigned u = __builtin_bit_cast(unsigned, f);
    u += 0x7FFF + ((u >> 16) & 1);           // round-to-nearest-even
    return (unsigned short)(u >> 16);
}

// ---------------------------------------------------------------------------
// f32 -> bf16 weight conversion (one-time per call, tiny)
// ---------------------------------------------------------------------------
__global__ __launch_bounds__(256)
void convert_f32_bf16(const float* __restrict__ src, short* __restrict__ dst, int n)
{
    int i = blockIdx.x * 256 + threadIdx.x;
    if (i < n) dst[i] = (short)f2bf(src[i]);
}

// ---------------------------------------------------------------------------
// Gather pass: f = set-order row, v = inds[f].
//   qk[f] = bf16(x[v] + pos[v]);  sf[f] = bf16(x[v])
// ---------------------------------------------------------------------------
__global__ __launch_bounds__(256)
void gather_kernel(const float* __restrict__ x, const float* __restrict__ pos,
                   const int* __restrict__ inds,
                   short* __restrict__ qk, short* __restrict__ sf)
{
    int f = blockIdx.x * 4 + (threadIdx.x >> 6);
    int lane = threadIdx.x & 63;
    if (lane >= 48) return;
    int v = inds[f];
    float4 a = *(const float4*)(x + (size_t)v * D_MODEL + lane * 4);
    float4 p = *(const float4*)(pos + (size_t)v * D_MODEL + lane * 4);
    s16x4 q, s;
    q[0] = (short)f2bf(a.x + p.x); q[1] = (short)f2bf(a.y + p.y);
    q[2] = (short)f2bf(a.z + p.z); q[3] = (short)f2bf(a.w + p.w);
    s[0] = (short)f2bf(a.x); s[1] = (short)f2bf(a.y);
    s[2] = (short)f2bf(a.z); s[3] = (short)f2bf(a.w);
    *(s16x4*)(qk + (size_t)f * D_MODEL + lane * 4) = q;
    *(s16x4*)(sf + (size_t)f * D_MODEL + lane * 4) = s;
}

// ---------------------------------------------------------------------------
// bf16 MFMA GEMM: C[row, colOff+colBase+c] = act(sum_k A[row,k]*W[colBase+c,k] + b[c])
// A (n,KTOT) bf16 row-major, W (O,KTOT) bf16 row-major, bias f32, C bf16.
// BM=128, BN=64, K staged 192 at a time. 256 thr = 4 waves, wave tile 64x32,
// mfma_f32_16x16x32_bf16, XOR-swizzled LDS (byte ^= (row&7)<<4).
// ---------------------------------------------------------------------------
template<int KTOT, bool RELU>
__global__ __launch_bounds__(256, 2)
void gemm_bf16(const short* __restrict__ A, const short* __restrict__ W,
               const float* __restrict__ bias, short* __restrict__ C,
               int n, int ldc, int colOff)
{
    __shared__ char lds[73728];            // As 128*384B + Bs 64*384B
    char* As = lds;
    char* Bs = lds + 49152;
    const int rowBase = blockIdx.x * 128;
    const int colBase = blockIdx.y * 64;
    const int tid = threadIdx.x;
    const int wid = tid >> 6, lane = tid & 63;
    const int waveM = wid >> 1, waveN = wid & 1;
    const int lr = lane & 15, kb = lane >> 4;

    f32x4 acc[4][2] = {};

    #pragma unroll
    for (int h = 0; h < KTOT / 192; ++h) {
        #pragma unroll
        for (int i = 0; i < 12; ++i) {          // A tile: 128 rows x 192 k
            int idx = i * 256 + tid;
            int row = idx / 24, c8 = idx % 24;
            int grow = rowBase + row;
            s16x8 v = {};
            if (grow < n) v = *(const s16x8*)(A + (size_t)grow * KTOT + h * 192 + c8 * 8);
            *(s16x8*)(As + row * 384 + ((c8 * 16) ^ ((row & 7) << 4))) = v;
        }
        #pragma unroll
        for (int i = 0; i < 6; ++i) {           // B tile: 64 cols x 192 k
            int idx = i * 256 + tid;
            int row = idx / 24, c8 = idx % 24;
            s16x8 v = *(const s16x8*)(W + (size_t)(colBase + row) * KTOT + h * 192 + c8 * 8);
            *(s16x8*)(Bs + row * 384 + ((c8 * 16) ^ ((row & 7) << 4))) = v;
        }
        __syncthreads();
        #pragma unroll
        for (int ks = 0; ks < 6; ++ks) {
            s16x8 a[4], b[2];
            #pragma unroll
            for (int fi = 0; fi < 4; ++fi) {
                int row = waveM * 64 + fi * 16 + lr;
                a[fi] = *(const s16x8*)(As + row * 384 + ((ks * 64 + kb * 16) ^ ((row & 7) << 4)));
            }
            #pragma unroll
            for (int fj = 0; fj < 2; ++fj) {
                int row = waveN * 32 + fj * 16 + lr;
                b[fj] = *(const s16x8*)(Bs + row * 384 + ((ks * 64 + kb * 16) ^ ((row & 7) << 4)));
            }
            #pragma unroll
            for (int fi = 0; fi < 4; ++fi)
                #pragma unroll
                for (int fj = 0; fj < 2; ++fj)
                    acc[fi][fj] = __builtin_amdgcn_mfma_f32_16x16x32_bf16(a[fi], b[fj], acc[fi][fj], 0, 0, 0);
        }
        __syncthreads();
    }

    #pragma unroll
    for (int fj = 0; fj < 2; ++fj) {
        int col = colBase + waveN * 32 + fj * 16 + lr;
        float bv = bias[col];
        #pragma unroll
        for (int fi = 0; fi < 4; ++fi) {
            #pragma unroll
            for (int r = 0; r < 4; ++r) {
                int grow = rowBase + waveM * 64 + fi * 16 + kb * 4 + r;
                if (grow < n) {
                    float v = acc[fi][fj][r] + bv;
                    if (RELU) v = fmaxf(v, 0.f);
                    C[(size_t)grow * ldc + colOff + col] = (short)f2bf(v);
                }
            }
        }
    }
}

// ---------------------------------------------------------------------------
// Attention: one wave per (set, head); bf16 I/O, f32 compute.
// qkv row f=(s*36+l): [0:192)=Q, [192:384)=K, [384:576)=V, head h at h*24.
// ---------------------------------------------------------------------------
__global__ __launch_bounds__(64)
void attn_kernel_bf(const short* __restrict__ qkv, const unsigned char* __restrict__ mask,
                    short* __restrict__ attn_out)
{
    const int s = blockIdx.x >> 3;
    const int h = blockIdx.x & 7;
    __shared__ float Ks[L_SET][H_DIM];
    __shared__ float Vs[L_SET][H_DIM];
    const int lane = threadIdx.x;

    for (int t = lane; t < L_SET * 3; t += 64) {   // 3x 8-bf16 chunks per row
        int l = t / 3, j = t % 3;
        size_t base = (size_t)(s * L_SET + l) * 576 + 192 + h * H_DIM + j * 8;
        s16x8 kv = *(const s16x8*)(qkv + base);
        s16x8 vv = *(const s16x8*)(qkv + base + 192);
        #pragma unroll
        for (int e = 0; e < 8; ++e) {
            Ks[l][j * 8 + e] = bf2f((unsigned short)kv[e]);
            Vs[l][j * 8 + e] = bf2f((unsigned short)vv[e]);
        }
    }
    __syncthreads();

    if (lane < L_SET) {
        float q[H_DIM];
        size_t qb = (size_t)(s * L_SET + lane) * 576 + h * H_DIM;
        #pragma unroll
        for (int j = 0; j < 3; ++j) {
            s16x8 t8 = *(const s16x8*)(qkv + qb + j * 8);
            #pragma unroll
            for (int e = 0; e < 8; ++e) q[j * 8 + e] = bf2f((unsigned short)t8[e]);
        }
        float sc[L_SET];
        float mx = -1e30f;
        #pragma unroll
        for (int m = 0; m < L_SET; ++m) {
            float a = 0.f;
            #pragma unroll
            for (int d = 0; d < H_DIM; ++d) a = fmaf(q[d], Ks[m][d], a);
            a *= 0.20412414523193154f;             // 1/sqrt(24)
            if (mask[(size_t)s * L_SET + m] != 0) a = -1e9f;
            sc[m] = a;
            mx = fmaxf(mx, a);
        }
        float ssum = 0.f;
        #pragma unroll
        for (int m = 0; m < L_SET; ++m) { float e = __expf(sc[m] - mx); sc[m] = e; ssum += e; }
        const float rinv = 1.f / ssum;
        float o[H_DIM];
        #pragma unroll
        for (int d = 0; d < H_DIM; ++d) o[d] = 0.f;
        #pragma unroll
        for (int m = 0; m < L_SET; ++m) {
            float p = sc[m] * rinv;
            #pragma unroll
            for (int d = 0; d < H_DIM; ++d) o[d] = fmaf(p, Vs[m][d], o[d]);
        }
        size_t ob = (size_t)(s * L_SET + lane) * D_MODEL + h * H_DIM;
        #pragma unroll
        for (int j = 0; j < 3; ++j) {
            s16x8 t8;
            #pragma unroll
            for (int e = 0; e < 8; ++e) t8[e] = (short)f2bf(o[j * 8 + e]);
            *(s16x8*)(attn_out + ob + j * 8) = t8;
        }
    }
}

// ---------------------------------------------------------------------------
__device__ __forceinline__ float wave_sum64(float v) {
    #pragma unroll
    for (int off = 32; off > 0; off >>= 1) v += __shfl_xor(v, off, 64);
    return v;
}

// LN1: x1[v] = bf16( LN(xin[v] + proj[f]) ), v = inds[f]
__global__ __launch_bounds__(256)
void ln_scatter_bf(const float* __restrict__ xin, const short* __restrict__ proj,
                   const int* __restrict__ inds,
                   const float* __restrict__ g, const float* __restrict__ be,
                   short* __restrict__ x1)
{
    int f = blockIdx.x * 4 + (threadIdx.x >> 6);
    int lane = threadIdx.x & 63;
    int v = inds[f];
    float4 t = make_float4(0.f, 0.f, 0.f, 0.f);
    if (lane < 48) {
        float4 a = *(const float4*)(xin + (size_t)v * D_MODEL + lane * 4);
        s16x4 p = *(const s16x4*)(proj + (size_t)f * D_MODEL + lane * 4);
        t.x = a.x + bf2f((unsigned short)p[0]);
        t.y = a.y + bf2f((unsigned short)p[1]);
        t.z = a.z + bf2f((unsigned short)p[2]);
        t.w = a.w + bf2f((unsigned short)p[3]);
    }
    float mean = wave_sum64(t.x + t.y + t.z + t.w) * (1.f / 192.f);
    float ss   = wave_sum64(t.x*t.x + t.y*t.y + t.z*t.z + t.w*t.w) * (1.f / 192.f);
    float inv = rsqrtf(ss - mean * mean + 1e-5f);
    if (lane < 48) {
        float4 gv = *(const float4*)(g + lane * 4);
        float4 bv = *(const float4*)(be + lane * 4);
        s16x4 o;
        o[0] = (short)f2bf((t.x - mean) * inv * gv.x + bv.x);
        o[1] = (short)f2bf((t.y - mean) * inv * gv.y + bv.y);
        o[2] = (short)f2bf((t.z - mean) * inv * gv.z + bv.z);
        o[3] = (short)f2bf((t.w - mean) * inv * gv.w + bv.w);
        *(s16x4*)(x1 + (size_t)v * D_MODEL + lane * 4) = o;
    }
}

// LN2+LN3: x2 = LN(x1[v]+f2[v]; g2,be2); out[v] = LN(x2 + xin[v]; gn,bn)  (f32 out)
__global__ __launch_bounds__(256)
void ln_double_bf(const short* __restrict__ x1, const short* __restrict__ f2,
                  const float* __restrict__ xin,
                  const float* __restrict__ g2, const float* __restrict__ be2,
                  const float* __restrict__ gn, const float* __restrict__ bn,
                  float* __restrict__ outp)
{
    int v = blockIdx.x * 4 + (threadIdx.x >> 6);
    int lane = threadIdx.x & 63;
    float4 t   = make_float4(0.f, 0.f, 0.f, 0.f);
    float4 idv = t, g2v = t, b2v = t, gnv = t, bnv = t;
    if (lane < 48) {
        s16x4 a = *(const s16x4*)(x1 + (size_t)v * D_MODEL + lane * 4);
        s16x4 b = *(const s16x4*)(f2 + (size_t)v * D_MODEL + lane * 4);
        idv = *(const float4*)(xin + (size_t)v * D_MODEL + lane * 4);
        t.x = bf2f((unsigned short)a[0]) + bf2f((unsigned short)b[0]);
        t.y = bf2f((unsigned short)a[1]) + bf2f((unsigned short)b[1]);
        t.z = bf2f((unsigned short)a[2]) + bf2f((unsigned short)b[2]);
        t.w = bf2f((unsigned short)a[3]) + bf2f((unsigned short)b[3]);
        g2v = *(const float4*)(g2 + lane * 4);
        b2v = *(const float4*)(be2 + lane * 4);
        gnv = *(const float4*)(gn + lane * 4);
        bnv = *(const float4*)(bn + lane * 4);
    }
    float m1 = wave_sum64(t.x + t.y + t.z + t.w) * (1.f / 192.f);
    float s1 = wave_sum64(t.x*t.x + t.y*t.y + t.z*t.z + t.w*t.w) * (1.f / 192.f);
    float i1 = rsqrtf(s1 - m1 * m1 + 1e-5f);
    float4 t2 = make_float4(0.f, 0.f, 0.f, 0.f);
    if (lane < 48) {
        t2.x = (t.x - m1) * i1 * g2v.x + b2v.x + idv.x;
        t2.y = (t.y - m1) * i1 * g2v.y + b2v.y + idv.y;
        t2.z = (t.z - m1) * i1 * g2v.z + b2v.z + idv.z;
        t2.w = (t.w - m1) * i1 * g2v.w + b2v.w + idv.w;
    }
    float m2 = wave_sum64(t2.x + t2.y + t2.z + t2.w) * (1.f / 192.f);
    float s2 = wave_sum64(t2.x*t2.x + t2.y*t2.y + t2.z*t2.z + t2.w*t2.w) * (1.f / 192.f);
    float i2 = rsqrtf(s2 - m2 * m2 + 1e-5f);
    if (lane < 48) {
        float4 o;
        o.x = (t2.x - m2) * i2 * gnv.x + bnv.x;
        o.y = (t2.y - m2) * i2 * gnv.y + bnv.y;
        o.z = (t2.z - m2) * i2 * gnv.z + bnv.z;
        o.w = (t2.w - m2) * i2 * gnv.w + bnv.w;
        *(float4*)(outp + (size_t)v * D_MODEL + lane * 4) = o;
    }
}

// ---------------------------------------------------------------------------
extern "C" void kernel_launch(void* const* d_in, const int* in_sizes, int n_in,
                              void* d_out, int out_size, void* d_ws, size_t ws_size,
                              hipStream_t stream)
{
    (void)in_sizes; (void)n_in; (void)out_size;
    const int N = NVOX;
    const float* src = (const float*)d_in[0];
    const int* inds[2] = {(const int*)d_in[1], (const int*)d_in[2]};
    const unsigned char* mask[2] = {(const unsigned char*)d_in[3], (const unsigned char*)d_in[4]};
    const float* pos[2] = {(const float*)d_in[5], (const float*)d_in[6]};
    const float* Wqkv = (const float*)d_in[7];
    const float* bqkv = (const float*)d_in[8];
    const float* Wo   = (const float*)d_in[9];
    const float* bo   = (const float*)d_in[10];
    const float* W1   = (const float*)d_in[11];
    const float* b1   = (const float*)d_in[12];
    const float* W2   = (const float*)d_in[13];
    const float* b2   = (const float*)d_in[14];
    const float* g1   = (const float*)d_in[15];
    const float* be1  = (const float*)d_in[16];
    const float* g2   = (const float*)d_in[17];
    const float* be2  = (const float*)d_in[18];
    const float* gn   = (const float*)d_in[19];
    const float* bn   = (const float*)d_in[20];

    float* out = (float*)d_out;
    short* wsS = (short*)d_ws;

    const size_t NE = (size_t)N * D_MODEL;          // 18,869,760
    // ws plan (bf16 shorts): weights [0, 589824); activations from 1M shorts.
    //   qk -> proj ; sf -> x1 ; qkv(3NE) -> h(2NE) ; attn -> f2
    short* wqkv_b = wsS;
    short* wo_b   = wsS + 221184;
    short* w1_b   = wsS + 294912;
    short* w2_b   = wsS + 442368;
    const size_t base = 1048576;
    short* qk   = wsS + base;
    short* sf   = qk + NE;
    short* qkvb = sf + NE;
    short* attnb = qkvb + 3 * NE;
    short* proj = qk;
    short* x1   = sf;
    short* hb   = qkvb;
    short* f2   = attnb;

    if (ws_size < (base + 6 * NE) * sizeof(short)) return;   // ~229 MB

    const dim3 blk(256);
    convert_f32_bf16<<<dim3(864), blk, 0, stream>>>(Wqkv, wqkv_b, 221184);
    convert_f32_bf16<<<dim3(288), blk, 0, stream>>>(Wo,   wo_b,   73728);
    convert_f32_bf16<<<dim3(576), blk, 0, stream>>>(W1,   w1_b,   147456);
    convert_f32_bf16<<<dim3(576), blk, 0, stream>>>(W2,   w2_b,   147456);

    for (int i = 0; i < 2; ++i) {
        const float* xin = (i == 0) ? src : out;
        gather_kernel<<<dim3(24570), blk, 0, stream>>>(xin, pos[i], inds[i], qk, sf);
        // Q,K projections (cols 0..383) from qk
        gemm_bf16<192, false><<<dim3(768, 6), blk, 0, stream>>>(
            qk, wqkv_b + (size_t)i * 110592, bqkv + i * 576, qkvb, N, 576, 0);
        // V projection (cols 384..575) from sf
        gemm_bf16<192, false><<<dim3(768, 3), blk, 0, stream>>>(
            sf, wqkv_b + (size_t)i * 110592 + 384 * 192, bqkv + i * 576 + 384, qkvb, N, 576, 384);
        attn_kernel_bf<<<dim3(S_SETS * N_HEADS), dim3(64), 0, stream>>>(qkvb, mask[i], attnb);
        gemm_bf16<192, false><<<dim3(768, 3), blk, 0, stream>>>(
            attnb, wo_b + (size_t)i * 36864, bo + i * 192, proj, N, 192, 0);
        ln_scatter_bf<<<dim3(24570), blk, 0, stream>>>(
            xin, proj, inds[i], g1 + i * 192, be1 + i * 192, x1);
        gemm_bf16<192, true><<<dim3(768, 6), blk, 0, stream>>>(
            x1, w1_b + (size_t)i * 73728, b1 + i * 384, hb, N, 384, 0);
        gemm_bf16<384, false><<<dim3(768, 3), blk, 0, stream>>>(
            hb, w2_b + (size_t)i * 73728, b2 + i * 192, f2, N, 192, 0);
        ln_double_bf<<<dim3(24570), blk, 0, stream>>>(
            x1, f2, xin, g2 + i * 192, be2 + i * 192, gn + i * 192, bn + i * 192, out);
    }
}

// Round 3
// 1044.779 us; speedup vs baseline: 2.2633x; 1.1056x over previous
//
#include <hip/hip_runtime.h>
#include <stdint.h>

#define NVOX   98280
#define S_SETS 2730
#define L_SET  36
#define D_MODEL 192
#define D_FF    384
#define N_HEADS 8
#define H_DIM   24

using s16x8 = __attribute__((ext_vector_type(8))) short;
using s16x4 = __attribute__((ext_vector_type(4))) short;
using f32x4 = __attribute__((ext_vector_type(4))) float;

__device__ __forceinline__ float bf2f(unsigned short h) {
    unsigned u = ((unsigned)h) << 16;
    return __builtin_bit_cast(float, u);
}
__device__ __forceinline__ unsigned short f2bf(float f) {
    unsigned u = __builtin_bit_cast(unsigned, f);
    u += 0x7FFF + ((u >> 16) & 1);           // round-to-nearest-even
    return (unsigned short)(u >> 16);
}

__global__ __launch_bounds__(256)
void convert_f32_bf16(const float* __restrict__ src, short* __restrict__ dst, int n)
{
    int i = blockIdx.x * 256 + threadIdx.x;
    if (i < n) dst[i] = (short)f2bf(src[i]);
}

// ---------------------------------------------------------------------------
// Register-resident-B GEMM.  C[row, colOff+c] = act(A[row,:] . W[c,:] + b[c])
// A (n,KTOT) bf16; W (N,KTOT) bf16 row-major; N = NW*CPW cols total.
// Block = NW waves; wave w owns cols [w*CPW, (w+1)*CPW), processed in CPW/32
// col-passes of 32 (acc[4][2], b[2][6] per k-half -> ~125 VGPR).
// Whole A row-tile (64 x KTOT) staged once in LDS, XOR-swizzled.
// A is read exactly ONCE per GEMM (no column-block re-fetch).
// ---------------------------------------------------------------------------
template<int KTOT, int NW, int CPW, bool RELU>
__global__ __launch_bounds__(NW * 64)
void gemm_breg(const short* __restrict__ A, const short* __restrict__ W,
               const float* __restrict__ bias, short* __restrict__ C,
               int n, int ldc, int colOff)
{
    __shared__ char As[64 * KTOT * 2];
    const int tid = threadIdx.x;
    const int wid = tid >> 6, lane = tid & 63;
    const int lr = lane & 15, kb = lane >> 4;
    const int rowBase = blockIdx.x * 64;

    // stage A tile (all of K)
    #pragma unroll
    for (int t = tid; t < 64 * KTOT / 8; t += NW * 64) {
        int row = t / (KTOT / 8), c8 = t % (KTOT / 8);
        int grow = rowBase + row;
        s16x8 v = {};
        if (grow < n) v = *(const s16x8*)(A + (size_t)grow * KTOT + c8 * 8);
        *(s16x8*)(As + row * (KTOT * 2) + ((c8 * 16) ^ ((row & 7) << 4))) = v;
    }
    __syncthreads();

    #pragma unroll
    for (int ch = 0; ch < CPW / 32; ++ch) {
        f32x4 acc[4][2] = {};
        #pragma unroll
        for (int h = 0; h < KTOT / 192; ++h) {
            s16x8 b[2][6];
            #pragma unroll
            for (int fj = 0; fj < 2; ++fj)
                #pragma unroll
                for (int ks = 0; ks < 6; ++ks)
                    b[fj][ks] = *(const s16x8*)(W +
                        (size_t)(wid * CPW + ch * 32 + fj * 16 + lr) * KTOT +
                        h * 192 + ks * 32 + kb * 8);
            #pragma unroll
            for (int ks = 0; ks < 6; ++ks) {
                s16x8 a[4];
                #pragma unroll
                for (int fi = 0; fi < 4; ++fi) {
                    int row = fi * 16 + lr;
                    a[fi] = *(const s16x8*)(As + row * (KTOT * 2) +
                        ((h * 384 + ks * 64 + kb * 16) ^ ((row & 7) << 4)));
                }
                #pragma unroll
                for (int fi = 0; fi < 4; ++fi)
                    #pragma unroll
                    for (int fj = 0; fj < 2; ++fj)
                        acc[fi][fj] = __builtin_amdgcn_mfma_f32_16x16x32_bf16(
                            a[fi], b[fj][ks], acc[fi][fj], 0, 0, 0);
            }
        }
        // epilogue for this 32-col pass
        #pragma unroll
        for (int fj = 0; fj < 2; ++fj) {
            int col = wid * CPW + ch * 32 + fj * 16 + lr;
            float bv = bias[col];
            #pragma unroll
            for (int fi = 0; fi < 4; ++fi) {
                #pragma unroll
                for (int r = 0; r < 4; ++r) {
                    int grow = rowBase + fi * 16 + kb * 4 + r;
                    if (grow < n) {
                        float v = acc[fi][fj][r] + bv;
                        if (RELU) v = fmaxf(v, 0.f);
                        C[(size_t)grow * ldc + colOff + col] = (short)f2bf(v);
                    }
                }
            }
        }
    }
}

// ---------------------------------------------------------------------------
// Fused gather + QKV GEMM. Rows in set-order f, v = inds[f].
// qk-tile = bf16(x[v]+pos[v]) feeds cols 0..383 (Q,K); sf-tile = bf16(x[v])
// feeds cols 384..575 (V). NW=6 waves x 96 cols. Out: qkvb (N,576) bf16.
// ---------------------------------------------------------------------------
__global__ __launch_bounds__(384)
void qkv_gemm_fused(const float* __restrict__ x, const float* __restrict__ pos,
                    const int* __restrict__ inds,
                    const short* __restrict__ W, const float* __restrict__ bias,
                    short* __restrict__ C, int n)
{
    __shared__ char Aqk[64 * 384];
    __shared__ char Asf[64 * 384];
    const int tid = threadIdx.x;
    const int wid = tid >> 6, lane = tid & 63;
    const int lr = lane & 15, kb = lane >> 4;
    const int rowBase = blockIdx.x * 64;

    // stage: gather x,pos (f32), convert, write both tiles
    #pragma unroll
    for (int t = tid; t < 3072; t += 384) {      // 64 rows x 48 float4-chunks
        int row = t / 48, c4 = t % 48;
        int grow = rowBase + row;
        float4 xa = make_float4(0.f, 0.f, 0.f, 0.f);
        float4 pa = xa;
        if (grow < n) {
            int v = inds[grow];
            xa = *(const float4*)(x + (size_t)v * D_MODEL + c4 * 4);
            pa = *(const float4*)(pos + (size_t)v * D_MODEL + c4 * 4);
        }
        s16x4 q, s;
        q[0] = (short)f2bf(xa.x + pa.x); q[1] = (short)f2bf(xa.y + pa.y);
        q[2] = (short)f2bf(xa.z + pa.z); q[3] = (short)f2bf(xa.w + pa.w);
        s[0] = (short)f2bf(xa.x); s[1] = (short)f2bf(xa.y);
        s[2] = (short)f2bf(xa.z); s[3] = (short)f2bf(xa.w);
        int off = row * 384 + ((c4 * 8) ^ ((row & 7) << 4));
        *(s16x4*)(Aqk + off) = q;
        *(s16x4*)(Asf + off) = s;
    }
    __syncthreads();

    const char* As = (wid < 4) ? Aqk : Asf;      // waves 0-3: cols 0-383 (Q,K); 4-5: V
    #pragma unroll
    for (int ch = 0; ch < 3; ++ch) {
        f32x4 acc[4][2] = {};
        s16x8 b[2][6];
        #pragma unroll
        for (int fj = 0; fj < 2; ++fj)
            #pragma unroll
            for (int ks = 0; ks < 6; ++ks)
                b[fj][ks] = *(const s16x8*)(W +
                    (size_t)(wid * 96 + ch * 32 + fj * 16 + lr) * 192 + ks * 32 + kb * 8);
        #pragma unroll
        for (int ks = 0; ks < 6; ++ks) {
            s16x8 a[4];
            #pragma unroll
            for (int fi = 0; fi < 4; ++fi) {
                int row = fi * 16 + lr;
                a[fi] = *(const s16x8*)(As + row * 384 +
                    ((ks * 64 + kb * 16) ^ ((row & 7) << 4)));
            }
            #pragma unroll
            for (int fi = 0; fi < 4; ++fi)
                #pragma unroll
                for (int fj = 0; fj < 2; ++fj)
                    acc[fi][fj] = __builtin_amdgcn_mfma_f32_16x16x32_bf16(
                        a[fi], b[fj][ks], acc[fi][fj], 0, 0, 0);
        }
        #pragma unroll
        for (int fj = 0; fj < 2; ++fj) {
            int col = wid * 96 + ch * 32 + fj * 16 + lr;
            float bv = bias[col];
            #pragma unroll
            for (int fi = 0; fi < 4; ++fi) {
                #pragma unroll
                for (int r = 0; r < 4; ++r) {
                    int grow = rowBase + fi * 16 + kb * 4 + r;
                    if (grow < n)
                        C[(size_t)grow * 576 + col] = (short)f2bf(acc[fi][fj][r] + bv);
                }
            }
        }
    }
}

// ---------------------------------------------------------------------------
// Attention: one block per SET, 8 waves = 8 heads. K,V converted once to f32
// LDS; score/PV reads are lane-broadcast (conflict-free) float4s.
// ---------------------------------------------------------------------------
__global__ __launch_bounds__(512)
void attn_set_kernel(const short* __restrict__ qkv, const unsigned char* __restrict__ mask,
                     short* __restrict__ attn_out)
{
    const int s = blockIdx.x;
    __shared__ float KV[2][L_SET][200];          // [K/V][row][192 f32 + pad]
    __shared__ int msk[L_SET];
    const int tid = threadIdx.x;
    const int wid = tid >> 6;                    // head
    const int lane = tid & 63;

    for (int t = tid; t < 1728; t += 512) {      // 2 matrices x 36 rows x 24 chunks
        int w = t >= 864;
        int u = t - (w ? 864 : 0);
        int l = u / 24, c8 = u % 24;
        s16x8 v = *(const s16x8*)(qkv + (size_t)(s * L_SET + l) * 576 + 192 + w * 192 + c8 * 8);
        #pragma unroll
        for (int e = 0; e < 8; ++e) KV[w][l][c8 * 8 + e] = bf2f((unsigned short)v[e]);
    }
    if (tid < L_SET) msk[tid] = mask[(size_t)s * L_SET + tid];
    __syncthreads();

    if (lane < L_SET) {
        float q[H_DIM];
        size_t qb = (size_t)(s * L_SET + lane) * 576 + wid * H_DIM;
        #pragma unroll
        for (int j = 0; j < 3; ++j) {
            s16x8 t8 = *(const s16x8*)(qkv + qb + j * 8);
            #pragma unroll
            for (int e = 0; e < 8; ++e) q[j * 8 + e] = bf2f((unsigned short)t8[e]);
        }
        float sc[L_SET];
        float mx = -1e30f;
        #pragma unroll
        for (int m = 0; m < L_SET; ++m) {
            float a = 0.f;
            #pragma unroll
            for (int j = 0; j < 6; ++j) {
                float4 k4 = *(const float4*)&KV[0][m][wid * H_DIM + j * 4];
                a = fmaf(q[j*4+0], k4.x, a); a = fmaf(q[j*4+1], k4.y, a);
                a = fmaf(q[j*4+2], k4.z, a); a = fmaf(q[j*4+3], k4.w, a);
            }
            a *= 0.20412414523193154f;           // 1/sqrt(24)
            if (msk[m] != 0) a = -1e9f;
            sc[m] = a;
            mx = fmaxf(mx, a);
        }
        float ssum = 0.f;
        #pragma unroll
        for (int m = 0; m < L_SET; ++m) { float e = __expf(sc[m] - mx); sc[m] = e; ssum += e; }
        const float rinv = 1.f / ssum;
        float o[H_DIM];
        #pragma unroll
        for (int d = 0; d < H_DIM; ++d) o[d] = 0.f;
        #pragma unroll
        for (int m = 0; m < L_SET; ++m) {
            float p = sc[m] * rinv;
            #pragma unroll
            for (int j = 0; j < 6; ++j) {
                float4 v4 = *(const float4*)&KV[1][m][wid * H_DIM + j * 4];
                o[j*4+0] = fmaf(p, v4.x, o[j*4+0]); o[j*4+1] = fmaf(p, v4.y, o[j*4+1]);
                o[j*4+2] = fmaf(p, v4.z, o[j*4+2]); o[j*4+3] = fmaf(p, v4.w, o[j*4+3]);
            }
        }
        size_t ob = (size_t)(s * L_SET + lane) * D_MODEL + wid * H_DIM;
        #pragma unroll
        for (int j = 0; j < 3; ++j) {
            s16x8 t8;
            #pragma unroll
            for (int e = 0; e < 8; ++e) t8[e] = (short)f2bf(o[j * 8 + e]);
            *(s16x8*)(attn_out + ob + j * 8) = t8;
        }
    }
}

// ---------------------------------------------------------------------------
__device__ __forceinline__ float wave_sum64(float v) {
    #pragma unroll
    for (int off = 32; off > 0; off >>= 1) v += __shfl_xor(v, off, 64);
    return v;
}

// LN1: x1[v] = bf16( LN(xin[v] + proj[f]) ), v = inds[f]
__global__ __launch_bounds__(256)
void ln_scatter_bf(const float* __restrict__ xin, const short* __restrict__ proj,
                   const int* __restrict__ inds,
                   const float* __restrict__ g, const float* __restrict__ be,
                   short* __restrict__ x1)
{
    int f = blockIdx.x * 4 + (threadIdx.x >> 6);
    int lane = threadIdx.x & 63;
    int v = inds[f];
    float4 t = make_float4(0.f, 0.f, 0.f, 0.f);
    if (lane < 48) {
        float4 a = *(const float4*)(xin + (size_t)v * D_MODEL + lane * 4);
        s16x4 p = *(const s16x4*)(proj + (size_t)f * D_MODEL + lane * 4);
        t.x = a.x + bf2f((unsigned short)p[0]);
        t.y = a.y + bf2f((unsigned short)p[1]);
        t.z = a.z + bf2f((unsigned short)p[2]);
        t.w = a.w + bf2f((unsigned short)p[3]);
    }
    float mean = wave_sum64(t.x + t.y + t.z + t.w) * (1.f / 192.f);
    float ss   = wave_sum64(t.x*t.x + t.y*t.y + t.z*t.z + t.w*t.w) * (1.f / 192.f);
    float inv = rsqrtf(ss - mean * mean + 1e-5f);
    if (lane < 48) {
        float4 gv = *(const float4*)(g + lane * 4);
        float4 bv = *(const float4*)(be + lane * 4);
        s16x4 o;
        o[0] = (short)f2bf((t.x - mean) * inv * gv.x + bv.x);
        o[1] = (short)f2bf((t.y - mean) * inv * gv.y + bv.y);
        o[2] = (short)f2bf((t.z - mean) * inv * gv.z + bv.z);
        o[3] = (short)f2bf((t.w - mean) * inv * gv.w + bv.w);
        *(s16x4*)(x1 + (size_t)v * D_MODEL + lane * 4) = o;
    }
}

// LN2+LN3: x2 = LN(x1[v]+f2[v]; g2,be2); out[v] = LN(x2 + xin[v]; gn,bn)  (f32 out)
__global__ __launch_bounds__(256)
void ln_double_bf(const short* __restrict__ x1, const short* __restrict__ f2,
                  const float* __restrict__ xin,
                  const float* __restrict__ g2, const float* __restrict__ be2,
                  const float* __restrict__ gn, const float* __restrict__ bn,
                  float* __restrict__ outp)
{
    int v = blockIdx.x * 4 + (threadIdx.x >> 6);
    int lane = threadIdx.x & 63;
    float4 t   = make_float4(0.f, 0.f, 0.f, 0.f);
    float4 idv = t, g2v = t, b2v = t, gnv = t, bnv = t;
    if (lane < 48) {
        s16x4 a = *(const s16x4*)(x1 + (size_t)v * D_MODEL + lane * 4);
        s16x4 b = *(const s16x4*)(f2 + (size_t)v * D_MODEL + lane * 4);
        idv = *(const float4*)(xin + (size_t)v * D_MODEL + lane * 4);
        t.x = bf2f((unsigned short)a[0]) + bf2f((unsigned short)b[0]);
        t.y = bf2f((unsigned short)a[1]) + bf2f((unsigned short)b[1]);
        t.z = bf2f((unsigned short)a[2]) + bf2f((unsigned short)b[2]);
        t.w = bf2f((unsigned short)a[3]) + bf2f((unsigned short)b[3]);
        g2v = *(const float4*)(g2 + lane * 4);
        b2v = *(const float4*)(be2 + lane * 4);
        gnv = *(const float4*)(gn + lane * 4);
        bnv = *(const float4*)(bn + lane * 4);
    }
    float m1 = wave_sum64(t.x + t.y + t.z + t.w) * (1.f / 192.f);
    float s1 = wave_sum64(t.x*t.x + t.y*t.y + t.z*t.z + t.w*t.w) * (1.f / 192.f);
    float i1 = rsqrtf(s1 - m1 * m1 + 1e-5f);
    float4 t2 = make_float4(0.f, 0.f, 0.f, 0.f);
    if (lane < 48) {
        t2.x = (t.x - m1) * i1 * g2v.x + b2v.x + idv.x;
        t2.y = (t.y - m1) * i1 * g2v.y + b2v.y + idv.y;
        t2.z = (t.z - m1) * i1 * g2v.z + b2v.z + idv.z;
        t2.w = (t.w - m1) * i1 * g2v.w + b2v.w + idv.w;
    }
    float m2 = wave_sum64(t2.x + t2.y + t2.z + t2.w) * (1.f / 192.f);
    float s2 = wave_sum64(t2.x*t2.x + t2.y*t2.y + t2.z*t2.z + t2.w*t2.w) * (1.f / 192.f);
    float i2 = rsqrtf(s2 - m2 * m2 + 1e-5f);
    if (lane < 48) {
        float4 o;
        o.x = (t2.x - m2) * i2 * gnv.x + bnv.x;
        o.y = (t2.y - m2) * i2 * gnv.y + bnv.y;
        o.z = (t2.z - m2) * i2 * gnv.z + bnv.z;
        o.w = (t2.w - m2) * i2 * gnv.w + bnv.w;
        *(float4*)(outp + (size_t)v * D_MODEL + lane * 4) = o;
    }
}

// ---------------------------------------------------------------------------
extern "C" void kernel_launch(void* const* d_in, const int* in_sizes, int n_in,
                              void* d_out, int out_size, void* d_ws, size_t ws_size,
                              hipStream_t stream)
{
    (void)in_sizes; (void)n_in; (void)out_size;
    const int N = NVOX;
    const float* src = (const float*)d_in[0];
    const int* inds[2] = {(const int*)d_in[1], (const int*)d_in[2]};
    const unsigned char* mask[2] = {(const unsigned char*)d_in[3], (const unsigned char*)d_in[4]};
    const float* pos[2] = {(const float*)d_in[5], (const float*)d_in[6]};
    const float* Wqkv = (const float*)d_in[7];
    const float* bqkv = (const float*)d_in[8];
    const float* Wo   = (const float*)d_in[9];
    const float* bo   = (const float*)d_in[10];
    const float* W1   = (const float*)d_in[11];
    const float* b1   = (const float*)d_in[12];
    const float* W2   = (const float*)d_in[13];
    const float* b2   = (const float*)d_in[14];
    const float* g1   = (const float*)d_in[15];
    const float* be1  = (const float*)d_in[16];
    const float* g2   = (const float*)d_in[17];
    const float* be2  = (const float*)d_in[18];
    const float* gn   = (const float*)d_in[19];
    const float* bn   = (const float*)d_in[20];

    float* out = (float*)d_out;
    short* wsS = (short*)d_ws;

    const size_t NE = (size_t)N * D_MODEL;          // 18,869,760
    // ws (shorts): weights [0, ~590K); activations from 1M.
    //   region0 3NE: qkvb -> { hb (first 2NE) , proj (last NE) }
    //   region1 1NE: attnb -> f2
    //   region2 1NE: x1
    short* wqkv_b = wsS;
    short* wo_b   = wsS + 221184;
    short* w1_b   = wsS + 294912;
    short* w2_b   = wsS + 442368;
    const size_t base = 1048576;
    short* qkvb  = wsS + base;
    short* hb    = qkvb;
    short* proj  = qkvb + 2 * NE;
    short* attnb = qkvb + 3 * NE;
    short* f2    = attnb;
    short* x1    = attnb + NE;

    if (ws_size < (base + 5 * NE) * sizeof(short)) return;   // ~191 MB

    const dim3 blk(256);
    convert_f32_bf16<<<dim3(864), blk, 0, stream>>>(Wqkv, wqkv_b, 221184);
    convert_f32_bf16<<<dim3(288), blk, 0, stream>>>(Wo,   wo_b,   73728);
    convert_f32_bf16<<<dim3(576), blk, 0, stream>>>(W1,   w1_b,   147456);
    convert_f32_bf16<<<dim3(576), blk, 0, stream>>>(W2,   w2_b,   147456);

    const int TILES = (N + 63) / 64;                 // 1536
    for (int i = 0; i < 2; ++i) {
        const float* xin = (i == 0) ? src : out;
        qkv_gemm_fused<<<dim3(TILES), dim3(384), 0, stream>>>(
            xin, pos[i], inds[i], wqkv_b + (size_t)i * 110592, bqkv + i * 576, qkvb, N);
        attn_set_kernel<<<dim3(S_SETS), dim3(512), 0, stream>>>(qkvb, mask[i], attnb);
        gemm_breg<192, 3, 64, false><<<dim3(TILES), dim3(192), 0, stream>>>(
            attnb, wo_b + (size_t)i * 36864, bo + i * 192, proj, N, 192, 0);
        ln_scatter_bf<<<dim3(24570), blk, 0, stream>>>(
            xin, proj, inds[i], g1 + i * 192, be1 + i * 192, x1);
        gemm_breg<192, 4, 96, true><<<dim3(TILES), dim3(256), 0, stream>>>(
            x1, w1_b + (size_t)i * 73728, b1 + i * 384, hb, N, 384, 0);
        gemm_breg<384, 3, 64, false><<<dim3(TILES), dim3(192), 0, stream>>>(
            hb, w2_b + (size_t)i * 73728, b2 + i * 192, f2, N, 192, 0);
        ln_double_bf<<<dim3(24570), blk, 0, stream>>>(
            x1, f2, xin, g2 + i * 192, be2 + i * 192, gn + i * 192, bn + i * 192, out);
    }
}

// Round 4
// 889.506 us; speedup vs baseline: 2.6583x; 1.1746x over previous
//
#include <hip/hip_runtime.h>
#include <stdint.h>

#define NVOX   98280
#define S_SETS 2730
#define L_SET  36
#define D_MODEL 192
#define D_FF    384
#define N_HEADS 8
#define H_DIM   24

using s16x8 = __attribute__((ext_vector_type(8))) short;
using s16x4 = __attribute__((ext_vector_type(4))) short;
using f32x4 = __attribute__((ext_vector_type(4))) float;

__device__ __forceinline__ float bf2f(unsigned short h) {
    unsigned u = ((unsigned)h) << 16;
    return __builtin_bit_cast(float, u);
}
__device__ __forceinline__ unsigned short f2bf(float f) {
    unsigned u = __builtin_bit_cast(unsigned, f);
    u += 0x7FFF + ((u >> 16) & 1);           // round-to-nearest-even
    return (unsigned short)(u >> 16);
}

__global__ __launch_bounds__(256)
void convert_f32_bf16(const float* __restrict__ src, short* __restrict__ dst, int n)
{
    int i = blockIdx.x * 256 + threadIdx.x;
    if (i < n) dst[i] = (short)f2bf(src[i]);
}

// ---------------------------------------------------------------------------
// Gather pass: f = set-order row, v = inds[f].
//   qk[f] = bf16(x[v] + pos[v]);  sf[f] = bf16(x[v])
// ---------------------------------------------------------------------------
__global__ __launch_bounds__(256)
void gather_kernel(const float* __restrict__ x, const float* __restrict__ pos,
                   const int* __restrict__ inds,
                   short* __restrict__ qk, short* __restrict__ sf)
{
    int f = blockIdx.x * 4 + (threadIdx.x >> 6);
    int lane = threadIdx.x & 63;
    if (lane >= 48) return;
    int v = inds[f];
    float4 a = *(const float4*)(x + (size_t)v * D_MODEL + lane * 4);
    float4 p = *(const float4*)(pos + (size_t)v * D_MODEL + lane * 4);
    s16x4 q, s;
    q[0] = (short)f2bf(a.x + p.x); q[1] = (short)f2bf(a.y + p.y);
    q[2] = (short)f2bf(a.z + p.z); q[3] = (short)f2bf(a.w + p.w);
    s[0] = (short)f2bf(a.x); s[1] = (short)f2bf(a.y);
    s[2] = (short)f2bf(a.z); s[3] = (short)f2bf(a.w);
    *(s16x4*)(qk + (size_t)f * D_MODEL + lane * 4) = q;
    *(s16x4*)(sf + (size_t)f * D_MODEL + lane * 4) = s;
}

// ---------------------------------------------------------------------------
// QKV GEMM: grid (768, 3); blockIdx.y = section {0:Q,1:K,2:V}.
// Block = 128 rows x 192 cols; B-section (192x192 bf16 = 73.7KB) in LDS.
// A read exactly once per section. 512 threads = 8 waves (4 rowx2 col).
// ---------------------------------------------------------------------------
__global__ __launch_bounds__(512)
void qkv_gemm3(const short* __restrict__ qk, const short* __restrict__ sf,
               const short* __restrict__ W, const float* __restrict__ bias,
               short* __restrict__ C, int n)
{
    extern __shared__ char pool[];
    char* As = pool;              // 128*384 = 49152
    char* Bs = pool + 49152;      // 192*384 = 73728
    const int sec = blockIdx.y;
    const short* Ap = (sec == 2) ? sf : qk;
    const short* Wp = W + (size_t)sec * 192 * 192;
    const int colOff = sec * 192;
    const int rowBase = blockIdx.x * 128;
    const int tid = threadIdx.x;

    #pragma unroll
    for (int t = tid; t < 3072; t += 512) {        // A: 128 rows x 24 chunks
        int row = t / 24, c8 = t % 24;
        int grow = rowBase + row;
        s16x8 v = {};
        if (grow < n) v = *(const s16x8*)(Ap + (size_t)grow * 192 + c8 * 8);
        *(s16x8*)(As + row * 384 + ((c8 * 16) ^ ((row & 7) << 4))) = v;
    }
    #pragma unroll
    for (int t = tid; t < 4608; t += 512) {        // B: 192 rows x 24 chunks
        int row = t / 24, c8 = t % 24;
        s16x8 v = *(const s16x8*)(Wp + (size_t)row * 192 + c8 * 8);
        *(s16x8*)(Bs + row * 384 + ((c8 * 16) ^ ((row & 7) << 4))) = v;
    }
    __syncthreads();

    const int wid = tid >> 6, lane = tid & 63;
    const int lr = lane & 15, kb = lane >> 4;
    const int wm = wid & 3, wn = wid >> 2;
    f32x4 acc[2][6] = {};
    #pragma unroll
    for (int ks = 0; ks < 6; ++ks) {
        s16x8 a[2], b[6];
        #pragma unroll
        for (int fi = 0; fi < 2; ++fi) {
            int row = wm * 32 + fi * 16 + lr;
            a[fi] = *(const s16x8*)(As + row * 384 + ((ks * 64 + kb * 16) ^ ((row & 7) << 4)));
        }
        #pragma unroll
        for (int fj = 0; fj < 6; ++fj) {
            int row = wn * 96 + fj * 16 + lr;
            b[fj] = *(const s16x8*)(Bs + row * 384 + ((ks * 64 + kb * 16) ^ ((row & 7) << 4)));
        }
        #pragma unroll
        for (int fi = 0; fi < 2; ++fi)
            #pragma unroll
            for (int fj = 0; fj < 6; ++fj)
                acc[fi][fj] = __builtin_amdgcn_mfma_f32_16x16x32_bf16(a[fi], b[fj], acc[fi][fj], 0, 0, 0);
    }
    #pragma unroll
    for (int fj = 0; fj < 6; ++fj) {
        int col = wn * 96 + fj * 16 + lr;
        float bv = bias[colOff + col];
        #pragma unroll
        for (int fi = 0; fi < 2; ++fi)
            #pragma unroll
            for (int r = 0; r < 4; ++r) {
                int grow = rowBase + wm * 32 + fi * 16 + kb * 4 + r;
                if (grow < n)
                    C[(size_t)grow * 576 + colOff + col] = (short)f2bf(acc[fi][fj][r] + bv);
            }
    }
}

// ---------------------------------------------------------------------------
// Attention: one block per SET, 8 waves = 8 heads (round-3 version).
// ---------------------------------------------------------------------------
__global__ __launch_bounds__(512)
void attn_set_kernel(const short* __restrict__ qkv, const unsigned char* __restrict__ mask,
                     short* __restrict__ attn_out)
{
    const int s = blockIdx.x;
    __shared__ float KV[2][L_SET][200];
    __shared__ int msk[L_SET];
    const int tid = threadIdx.x;
    const int wid = tid >> 6;
    const int lane = tid & 63;

    for (int t = tid; t < 1728; t += 512) {
        int w = t >= 864;
        int u = t - (w ? 864 : 0);
        int l = u / 24, c8 = u % 24;
        s16x8 v = *(const s16x8*)(qkv + (size_t)(s * L_SET + l) * 576 + 192 + w * 192 + c8 * 8);
        #pragma unroll
        for (int e = 0; e < 8; ++e) KV[w][l][c8 * 8 + e] = bf2f((unsigned short)v[e]);
    }
    if (tid < L_SET) msk[tid] = mask[(size_t)s * L_SET + tid];
    __syncthreads();

    if (lane < L_SET) {
        float q[H_DIM];
        size_t qb = (size_t)(s * L_SET + lane) * 576 + wid * H_DIM;
        #pragma unroll
        for (int j = 0; j < 3; ++j) {
            s16x8 t8 = *(const s16x8*)(qkv + qb + j * 8);
            #pragma unroll
            for (int e = 0; e < 8; ++e) q[j * 8 + e] = bf2f((unsigned short)t8[e]);
        }
        float sc[L_SET];
        float mx = -1e30f;
        #pragma unroll
        for (int m = 0; m < L_SET; ++m) {
            float a = 0.f;
            #pragma unroll
            for (int j = 0; j < 6; ++j) {
                float4 k4 = *(const float4*)&KV[0][m][wid * H_DIM + j * 4];
                a = fmaf(q[j*4+0], k4.x, a); a = fmaf(q[j*4+1], k4.y, a);
                a = fmaf(q[j*4+2], k4.z, a); a = fmaf(q[j*4+3], k4.w, a);
            }
            a *= 0.20412414523193154f;
            if (msk[m] != 0) a = -1e9f;
            sc[m] = a;
            mx = fmaxf(mx, a);
        }
        float ssum = 0.f;
        #pragma unroll
        for (int m = 0; m < L_SET; ++m) { float e = __expf(sc[m] - mx); sc[m] = e; ssum += e; }
        const float rinv = 1.f / ssum;
        float o[H_DIM];
        #pragma unroll
        for (int d = 0; d < H_DIM; ++d) o[d] = 0.f;
        #pragma unroll
        for (int m = 0; m < L_SET; ++m) {
            float p = sc[m] * rinv;
            #pragma unroll
            for (int j = 0; j < 6; ++j) {
                float4 v4 = *(const float4*)&KV[1][m][wid * H_DIM + j * 4];
                o[j*4+0] = fmaf(p, v4.x, o[j*4+0]); o[j*4+1] = fmaf(p, v4.y, o[j*4+1]);
                o[j*4+2] = fmaf(p, v4.z, o[j*4+2]); o[j*4+3] = fmaf(p, v4.w, o[j*4+3]);
            }
        }
        size_t ob = (size_t)(s * L_SET + lane) * D_MODEL + wid * H_DIM;
        #pragma unroll
        for (int j = 0; j < 3; ++j) {
            s16x8 t8;
            #pragma unroll
            for (int e = 0; e < 8; ++e) t8[e] = (short)f2bf(o[j * 8 + e]);
            *(s16x8*)(attn_out + ob + j * 8) = t8;
        }
    }
}

__device__ __forceinline__ float wave_sum64(float v) {
    #pragma unroll
    for (int off = 32; off > 0; off >>= 1) v += __shfl_xor(v, off, 64);
    return v;
}

// ---------------------------------------------------------------------------
// Wo GEMM + LN1 fused. Block = 128 set-order rows x all 192 cols, Wo in LDS.
// Epilogue: C -> LDS f32, then per-row LN(xin[v] + C) scatter-written to x1[v].
// ---------------------------------------------------------------------------
__global__ __launch_bounds__(512)
void wo_ln1(const short* __restrict__ attnb, const short* __restrict__ Wo,
            const float* __restrict__ bo, const int* __restrict__ inds,
            const float* __restrict__ xin,
            const float* __restrict__ g1, const float* __restrict__ be1,
            short* __restrict__ x1, int n)
{
    extern __shared__ char pool[];
    char* As = pool;              // 49152
    char* Bs = pool + 49152;      // 73728
    float* Cf = (float*)pool;     // 128*192 f32 = 98304 (reused after MFMA)
    const int rowBase = blockIdx.x * 128;
    const int tid = threadIdx.x;

    #pragma unroll
    for (int t = tid; t < 3072; t += 512) {
        int row = t / 24, c8 = t % 24;
        int grow = rowBase + row;
        s16x8 v = {};
        if (grow < n) v = *(const s16x8*)(attnb + (size_t)grow * 192 + c8 * 8);
        *(s16x8*)(As + row * 384 + ((c8 * 16) ^ ((row & 7) << 4))) = v;
    }
    #pragma unroll
    for (int t = tid; t < 4608; t += 512) {
        int row = t / 24, c8 = t % 24;
        s16x8 v = *(const s16x8*)(Wo + (size_t)row * 192 + c8 * 8);
        *(s16x8*)(Bs + row * 384 + ((c8 * 16) ^ ((row & 7) << 4))) = v;
    }
    __syncthreads();

    const int wid = tid >> 6, lane = tid & 63;
    const int lr = lane & 15, kb = lane >> 4;
    const int wm = wid & 3, wn = wid >> 2;
    f32x4 acc[2][6] = {};
    #pragma unroll
    for (int ks = 0; ks < 6; ++ks) {
        s16x8 a[2], b[6];
        #pragma unroll
        for (int fi = 0; fi < 2; ++fi) {
            int row = wm * 32 + fi * 16 + lr;
            a[fi] = *(const s16x8*)(As + row * 384 + ((ks * 64 + kb * 16) ^ ((row & 7) << 4)));
        }
        #pragma unroll
        for (int fj = 0; fj < 6; ++fj) {
            int row = wn * 96 + fj * 16 + lr;
            b[fj] = *(const s16x8*)(Bs + row * 384 + ((ks * 64 + kb * 16) ^ ((row & 7) << 4)));
        }
        #pragma unroll
        for (int fi = 0; fi < 2; ++fi)
            #pragma unroll
            for (int fj = 0; fj < 6; ++fj)
                acc[fi][fj] = __builtin_amdgcn_mfma_f32_16x16x32_bf16(a[fi], b[fj], acc[fi][fj], 0, 0, 0);
    }
    __syncthreads();                               // all LDS reads done
    #pragma unroll
    for (int fj = 0; fj < 6; ++fj) {
        int col = wn * 96 + fj * 16 + lr;
        float bv = bo[col];
        #pragma unroll
        for (int fi = 0; fi < 2; ++fi)
            #pragma unroll
            for (int r = 0; r < 4; ++r) {
                int row = wm * 32 + fi * 16 + kb * 4 + r;
                Cf[row * 192 + col] = acc[fi][fj][r] + bv;
            }
    }
    __syncthreads();

    // LN phase: wave w owns rows w*16 .. w*16+15; prefetch gathers first.
    int vv[16];
    #pragma unroll
    for (int i = 0; i < 16; ++i) {
        int f = rowBase + wid * 16 + i;
        vv[i] = (f < n) ? inds[f] : 0;
    }
    float4 xr[16];
    #pragma unroll
    for (int i = 0; i < 16; ++i)
        xr[i] = (lane < 48) ? *(const float4*)(xin + (size_t)vv[i] * D_MODEL + lane * 4)
                            : make_float4(0.f, 0.f, 0.f, 0.f);
    float4 gv = (lane < 48) ? *(const float4*)(g1 + lane * 4) : make_float4(0,0,0,0);
    float4 bv = (lane < 48) ? *(const float4*)(be1 + lane * 4) : make_float4(0,0,0,0);
    #pragma unroll
    for (int i = 0; i < 16; ++i) {
        int r = wid * 16 + i;
        int f = rowBase + r;
        float4 t = make_float4(0.f, 0.f, 0.f, 0.f);
        if (lane < 48) {
            float4 c4 = *(const float4*)&Cf[r * 192 + lane * 4];
            t.x = c4.x + xr[i].x; t.y = c4.y + xr[i].y;
            t.z = c4.z + xr[i].z; t.w = c4.w + xr[i].w;
        }
        float mean = wave_sum64(t.x + t.y + t.z + t.w) * (1.f / 192.f);
        float ss   = wave_sum64(t.x*t.x + t.y*t.y + t.z*t.z + t.w*t.w) * (1.f / 192.f);
        float inv = rsqrtf(ss - mean * mean + 1e-5f);
        if (lane < 48 && f < n) {
            s16x4 o;
            o[0] = (short)f2bf((t.x - mean) * inv * gv.x + bv.x);
            o[1] = (short)f2bf((t.y - mean) * inv * gv.y + bv.y);
            o[2] = (short)f2bf((t.z - mean) * inv * gv.z + bv.z);
            o[3] = (short)f2bf((t.w - mean) * inv * gv.w + bv.w);
            *(s16x4*)(x1 + (size_t)vv[i] * D_MODEL + lane * 4) = o;
        }
    }
}

// ---------------------------------------------------------------------------
// FFN fused: h = relu(x1@W1^T+b1) in LDS chunks (never to HBM);
// f2 = h@W2^T+b2 accumulated in regs; epilogue LN2(x1+f2) + identity + LN3.
// Block = 128 voxel rows. LDS: Ax 49152 | W1c 36864 | W2c 39936 | Hc 26624.
// ---------------------------------------------------------------------------
__global__ __launch_bounds__(512)
void ffn_fused(const short* __restrict__ x1, const short* __restrict__ W1,
               const float* __restrict__ b1, const short* __restrict__ W2,
               const float* __restrict__ b2, const float* __restrict__ xin,
               const float* __restrict__ g2, const float* __restrict__ be2,
               const float* __restrict__ gn, const float* __restrict__ bn,
               float* __restrict__ outp, int n)
{
    extern __shared__ char pool[];
    char* Ax  = pool;                  // x1 tile bf16 swz: 128*384
    char* W1c = pool + 49152;          // 96 rows * 384B swz
    char* W2c = pool + 86016;          // 192 rows * 208B (pad, no swz)
    char* Hc  = pool + 125952;         // 128 rows * 208B (pad, no swz)
    float* Cf = (float*)(pool + 49152);// 128*192 f32 (reused after chunks)
    const int rowBase = blockIdx.x * 128;
    const int tid = threadIdx.x;
    const int wid = tid >> 6, lane = tid & 63;
    const int lr = lane & 15, kb = lane >> 4;
    const int wm = wid & 3, wn = wid >> 2;

    #pragma unroll
    for (int t = tid; t < 3072; t += 512) {        // stage x1 tile
        int row = t / 24, c8 = t % 24;
        int grow = rowBase + row;
        s16x8 v = {};
        if (grow < n) v = *(const s16x8*)(x1 + (size_t)grow * 192 + c8 * 8);
        *(s16x8*)(Ax + row * 384 + ((c8 * 16) ^ ((row & 7) << 4))) = v;
    }

    f32x4 acc2[2][6] = {};
    for (int c = 0; c < 4; ++c) {                  // 4 chunks of 96 FF-dims
        __syncthreads();                           // prior chunk done with W/Hc
        #pragma unroll
        for (int t = tid; t < 2304; t += 512) {    // W1 chunk: 96 rows x 192K
            int row = t / 24, c8 = t % 24;
            s16x8 v = *(const s16x8*)(W1 + (size_t)(c * 96 + row) * 192 + c8 * 8);
            *(s16x8*)(W1c + row * 384 + ((c8 * 16) ^ ((row & 7) << 4))) = v;
        }
        #pragma unroll
        for (int t = tid; t < 2304; t += 512) {    // W2 chunk: 192 rows x 96K
            int row = t / 12, c8 = t % 12;
            s16x8 v = *(const s16x8*)(W2 + (size_t)row * 384 + c * 96 + c8 * 8);
            *(s16x8*)(W2c + row * 208 + c8 * 16) = v;
        }
        __syncthreads();
        // FF1: (128 x 96chunk) = Ax @ W1c^T ; wave tile 32 x 48
        f32x4 acc1[2][3] = {};
        #pragma unroll
        for (int ks = 0; ks < 6; ++ks) {
            s16x8 a[2], b[3];
            #pragma unroll
            for (int fi = 0; fi < 2; ++fi) {
                int row = wm * 32 + fi * 16 + lr;
                a[fi] = *(const s16x8*)(Ax + row * 384 + ((ks * 64 + kb * 16) ^ ((row & 7) << 4)));
            }
            #pragma unroll
            for (int fj = 0; fj < 3; ++fj) {
                int row = wn * 48 + fj * 16 + lr;
                b[fj] = *(const s16x8*)(W1c + row * 384 + ((ks * 64 + kb * 16) ^ ((row & 7) << 4)));
            }
            #pragma unroll
            for (int fi = 0; fi < 2; ++fi)
                #pragma unroll
                for (int fj = 0; fj < 3; ++fj)
                    acc1[fi][fj] = __builtin_amdgcn_mfma_f32_16x16x32_bf16(a[fi], b[fj], acc1[fi][fj], 0, 0, 0);
        }
        #pragma unroll
        for (int fj = 0; fj < 3; ++fj) {
            int col = wn * 48 + fj * 16 + lr;
            float b1v = b1[c * 96 + col];
            #pragma unroll
            for (int fi = 0; fi < 2; ++fi)
                #pragma unroll
                for (int r = 0; r < 4; ++r) {
                    int row = wm * 32 + fi * 16 + kb * 4 + r;
                    *(short*)(Hc + row * 208 + col * 2) =
                        (short)f2bf(fmaxf(acc1[fi][fj][r] + b1v, 0.f));
                }
        }
        __syncthreads();
        // FF2 partial: acc2 += Hc(128x96) @ W2c^T(192x96)
        #pragma unroll
        for (int ks = 0; ks < 3; ++ks) {
            s16x8 a[2], b[6];
            #pragma unroll
            for (int fi = 0; fi < 2; ++fi) {
                int row = wm * 32 + fi * 16 + lr;
                a[fi] = *(const s16x8*)(Hc + row * 208 + ks * 64 + kb * 16);
            }
            #pragma unroll
            for (int fj = 0; fj < 6; ++fj) {
                int row = wn * 96 + fj * 16 + lr;
                b[fj] = *(const s16x8*)(W2c + row * 208 + ks * 64 + kb * 16);
            }
            #pragma unroll
            for (int fi = 0; fi < 2; ++fi)
                #pragma unroll
                for (int fj = 0; fj < 6; ++fj)
                    acc2[fi][fj] = __builtin_amdgcn_mfma_f32_16x16x32_bf16(a[fi], b[fj], acc2[fi][fj], 0, 0, 0);
        }
    }
    __syncthreads();
    #pragma unroll
    for (int fj = 0; fj < 6; ++fj) {
        int col = wn * 96 + fj * 16 + lr;
        float bv = b2[col];
        #pragma unroll
        for (int fi = 0; fi < 2; ++fi)
            #pragma unroll
            for (int r = 0; r < 4; ++r) {
                int row = wm * 32 + fi * 16 + kb * 4 + r;
                Cf[row * 192 + col] = acc2[fi][fj][r] + bv;
            }
    }
    __syncthreads();

    // LN2 + identity + LN3. wave w owns rows w*16..w*16+15 (voxel order).
    float4 xr[16];
    #pragma unroll
    for (int i = 0; i < 16; ++i) {
        int gvx = rowBase + wid * 16 + i;
        xr[i] = (lane < 48 && gvx < n)
              ? *(const float4*)(xin + (size_t)gvx * D_MODEL + lane * 4)
              : make_float4(0.f, 0.f, 0.f, 0.f);
    }
    float4 g2v = (lane < 48) ? *(const float4*)(g2 + lane * 4) : make_float4(0,0,0,0);
    float4 b2v = (lane < 48) ? *(const float4*)(be2 + lane * 4) : make_float4(0,0,0,0);
    float4 gnv = (lane < 48) ? *(const float4*)(gn + lane * 4) : make_float4(0,0,0,0);
    float4 bnv = (lane < 48) ? *(const float4*)(bn + lane * 4) : make_float4(0,0,0,0);
    #pragma unroll
    for (int i = 0; i < 16; ++i) {
        int r = wid * 16 + i;
        int gvx = rowBase + r;
        float4 t = make_float4(0.f, 0.f, 0.f, 0.f);
        if (lane < 48) {
            float4 f4 = *(const float4*)&Cf[r * 192 + lane * 4];
            // x1 (bf16) from Ax LDS: 8 bytes at elem lane*4
            int byteoff = r * 384 + ((((lane >> 1) << 4) ^ ((r & 7) << 4))) + ((lane & 1) << 3);
            s16x4 xv = *(const s16x4*)(Ax + byteoff);
            t.x = f4.x + bf2f((unsigned short)xv[0]);
            t.y = f4.y + bf2f((unsigned short)xv[1]);
            t.z = f4.z + bf2f((unsigned short)xv[2]);
            t.w = f4.w + bf2f((unsigned short)xv[3]);
        }
        float m1 = wave_sum64(t.x + t.y + t.z + t.w) * (1.f / 192.f);
        float s1 = wave_sum64(t.x*t.x + t.y*t.y + t.z*t.z + t.w*t.w) * (1.f / 192.f);
        float i1 = rsqrtf(s1 - m1 * m1 + 1e-5f);
        float4 t2 = make_float4(0.f, 0.f, 0.f, 0.f);
        if (lane < 48) {
            t2.x = (t.x - m1) * i1 * g2v.x + b2v.x + xr[i].x;
            t2.y = (t.y - m1) * i1 * g2v.y + b2v.y + xr[i].y;
            t2.z = (t.z - m1) * i1 * g2v.z + b2v.z + xr[i].z;
            t2.w = (t.w - m1) * i1 * g2v.w + b2v.w + xr[i].w;
        }
        float m2 = wave_sum64(t2.x + t2.y + t2.z + t2.w) * (1.f / 192.f);
        float s2 = wave_sum64(t2.x*t2.x + t2.y*t2.y + t2.z*t2.z + t2.w*t2.w) * (1.f / 192.f);
        float i2 = rsqrtf(s2 - m2 * m2 + 1e-5f);
        if (lane < 48 && gvx < n) {
            float4 o;
            o.x = (t2.x - m2) * i2 * gnv.x + bnv.x;
            o.y = (t2.y - m2) * i2 * gnv.y + bnv.y;
            o.z = (t2.z - m2) * i2 * gnv.z + bnv.z;
            o.w = (t2.w - m2) * i2 * gnv.w + bnv.w;
            *(float4*)(outp + (size_t)gvx * D_MODEL + lane * 4) = o;
        }
    }
}

// ---------------------------------------------------------------------------
extern "C" void kernel_launch(void* const* d_in, const int* in_sizes, int n_in,
                              void* d_out, int out_size, void* d_ws, size_t ws_size,
                              hipStream_t stream)
{
    (void)in_sizes; (void)n_in; (void)out_size;
    const int N = NVOX;
    const float* src = (const float*)d_in[0];
    const int* inds[2] = {(const int*)d_in[1], (const int*)d_in[2]};
    const unsigned char* mask[2] = {(const unsigned char*)d_in[3], (const unsigned char*)d_in[4]};
    const float* pos[2] = {(const float*)d_in[5], (const float*)d_in[6]};
    const float* Wqkv = (const float*)d_in[7];
    const float* bqkv = (const float*)d_in[8];
    const float* Wo   = (const float*)d_in[9];
    const float* bo   = (const float*)d_in[10];
    const float* W1   = (const float*)d_in[11];
    const float* b1   = (const float*)d_in[12];
    const float* W2   = (const float*)d_in[13];
    const float* b2   = (const float*)d_in[14];
    const float* g1   = (const float*)d_in[15];
    const float* be1  = (const float*)d_in[16];
    const float* g2   = (const float*)d_in[17];
    const float* be2  = (const float*)d_in[18];
    const float* gn   = (const float*)d_in[19];
    const float* bn   = (const float*)d_in[20];

    float* out = (float*)d_out;
    short* wsS = (short*)d_ws;

    const size_t NE = (size_t)N * D_MODEL;
    short* wqkv_b = wsS;
    short* wo_b   = wsS + 221184;
    short* w1_b   = wsS + 294912;
    short* w2_b   = wsS + 442368;
    const size_t base = 1048576;
    short* qk    = wsS + base;
    short* sf    = qk + NE;
    short* qkvb  = sf + NE;
    short* attnb = qkvb + 3 * NE;
    short* x1    = attnb + NE;

    if (ws_size < (base + 7 * NE) * sizeof(short)) return;   // ~266 MB

    const dim3 blk(256);
    convert_f32_bf16<<<dim3(864), blk, 0, stream>>>(Wqkv, wqkv_b, 221184);
    convert_f32_bf16<<<dim3(288), blk, 0, stream>>>(Wo,   wo_b,   73728);
    convert_f32_bf16<<<dim3(576), blk, 0, stream>>>(W1,   w1_b,   147456);
    convert_f32_bf16<<<dim3(576), blk, 0, stream>>>(W2,   w2_b,   147456);

    const int RT = (N + 127) / 128;                  // 768 row tiles
    for (int i = 0; i < 2; ++i) {
        const float* xin = (i == 0) ? src : out;
        gather_kernel<<<dim3(24570), blk, 0, stream>>>(xin, pos[i], inds[i], qk, sf);
        qkv_gemm3<<<dim3(RT, 3), dim3(512), 122880, stream>>>(
            qk, sf, wqkv_b + (size_t)i * 110592, bqkv + i * 576, qkvb, N);
        attn_set_kernel<<<dim3(S_SETS), dim3(512), 0, stream>>>(qkvb, mask[i], attnb);
        wo_ln1<<<dim3(RT), dim3(512), 122880, stream>>>(
            attnb, wo_b + (size_t)i * 36864, bo + i * 192, inds[i], xin,
            g1 + i * 192, be1 + i * 192, x1, N);
        ffn_fused<<<dim3(RT), dim3(512), 152576, stream>>>(
            x1, w1_b + (size_t)i * 73728, b1 + i * 384, w2_b + (size_t)i * 73728,
            b2 + i * 192, xin, g2 + i * 192, be2 + i * 192,
            gn + i * 192, bn + i * 192, out, N);
    }
}